// Round 7
// baseline (5307.403 us; speedup 1.0000x reference)
//
#include <hip/hip_runtime.h>
#include <stdint.h>

#define BATCH 8
#define K 65536
#define CFEAT 128
#define NPROP 1024
#define M 16            // workgroups per batch
#define T 256           // threads per WG
#define PTS (K / M)     // 4096 points per WG
#define PPT (PTS / T)   // 16 points per thread

// d_out layout (float32): new_xyz (B,N,3) | new_features (B,C,N) | inds (B,N) as float
#define OUT_FEAT (BATCH * NPROP * 3)                         // 24576
#define OUT_INDS (BATCH * NPROP * 3 + BATCH * CFEAT * NPROP) // 1073152

// ws layout, two regions of [2][BATCH][M] 64B lines each:
//   mirror (offset 0):      [0]=key{dist|0xFFFF-g|tag} [1]={tag|z} [2]={tag|x} [3]={tag|y}
//   safe   (offset 2048 ull): [0]=key only (r3 protocol, round-3 validated 1670us)
// MIRROR is an OPPORTUNISTIC L2 fast path: all 16 WGs of a batch land on one
// XCD under the current blockIdx%8 dispatch map, so sc0 loads (L1-bypass,
// L2-service, ~250cy RTT) see same-XCD stores ~3x faster than the agent-scope
// (sc1, coherence-point ~700cy) path. If the mapping ever changes, cross-XCD
// readers see STALE lines (never invalid new data), every word self-validates
// via its 16-bit tag, and the bounded fast loop falls back to the agent-scope
// safe copy — correctness never depends on WG->XCD placement (Guideline 16).
// Parity double-buffer + exact tags: a WG posts round t only after finishing
// its poll of round t-1, which requires all WGs posted t-1, which requires
// all WGs finished polling t-2 (same parity) — overwrite races impossible.
#define SLOT_STRIDE 8
#define MIRROR_ULLS (2 * BATCH * M * SLOT_STRIDE)   // 2048
#define WS_ULLS (2 * MIRROR_ULLS)                   // 4096 ulls = 32 KB
#define FAST_ITERS 24   // ~6K cy of L2 polling before agent-scope fallback

typedef unsigned int u32x4 __attribute__((ext_vector_type(4)));

__global__ __launch_bounds__(256) void fps_init(unsigned long long* ws) {
    int i = blockIdx.x * 256 + threadIdx.x;
    if (i < WS_ULLS) ws[i] = 0ull;   // tag 0 never matches t in [1,1023]
}

// Wave-wide u32 max via DPP (HW-validated rounds 2-6). Max lands in lane 63.
__device__ __forceinline__ unsigned int wave_umax63(unsigned int x) {
    int v = (int)x;
    int t;
    t = __builtin_amdgcn_update_dpp(v, v, 0x111, 0xF, 0xF, false);  // row_shr:1
    v = ((unsigned)t > (unsigned)v) ? t : v;
    t = __builtin_amdgcn_update_dpp(v, v, 0x112, 0xF, 0xF, false);  // row_shr:2
    v = ((unsigned)t > (unsigned)v) ? t : v;
    t = __builtin_amdgcn_update_dpp(v, v, 0x114, 0xF, 0xF, false);  // row_shr:4
    v = ((unsigned)t > (unsigned)v) ? t : v;
    t = __builtin_amdgcn_update_dpp(v, v, 0x118, 0xF, 0xF, false);  // row_shr:8
    v = ((unsigned)t > (unsigned)v) ? t : v;
    t = __builtin_amdgcn_update_dpp(v, v, 0x142, 0xF, 0xF, false);  // row_bcast:15
    v = ((unsigned)t > (unsigned)v) ? t : v;
    t = __builtin_amdgcn_update_dpp(v, v, 0x143, 0xF, 0xF, false);  // row_bcast:31
    v = ((unsigned)t > (unsigned)v) ? t : v;
    return (unsigned int)v;
}

// 16-lane (row 0) u32 max via DPP; max of lanes 0..15 lands in lane 15.
__device__ __forceinline__ unsigned int row16_umax15(unsigned int x) {
    int v = (int)x;
    int t;
    t = __builtin_amdgcn_update_dpp(v, v, 0x111, 0xF, 0xF, false);  // row_shr:1
    v = ((unsigned)t > (unsigned)v) ? t : v;
    t = __builtin_amdgcn_update_dpp(v, v, 0x112, 0xF, 0xF, false);  // row_shr:2
    v = ((unsigned)t > (unsigned)v) ? t : v;
    t = __builtin_amdgcn_update_dpp(v, v, 0x114, 0xF, 0xF, false);  // row_shr:4
    v = ((unsigned)t > (unsigned)v) ? t : v;
    t = __builtin_amdgcn_update_dpp(v, v, 0x118, 0xF, 0xF, false);  // row_shr:8
    v = ((unsigned)t > (unsigned)v) ? t : v;
    return (unsigned int)v;
}

// 32B line read with sc0 (L1-bypass, L2-service). Per-lane address.
__device__ __forceinline__ void load_line_sc0(const unsigned long long* p,
                                              u32x4& a, u32x4& bq) {
    asm volatile("global_load_dwordx4 %0, %2, off sc0\n\t"
                 "global_load_dwordx4 %1, %2, off offset:16 sc0\n\t"
                 "s_waitcnt vmcnt(0)"
                 : "=&v"(a), "=&v"(bq)
                 : "v"(p)
                 : "memory");
}

__global__ __launch_bounds__(T) void fps_kernel(const float* __restrict__ xyz,
                                                float* __restrict__ out,
                                                unsigned long long* __restrict__ ws) {
    const int b = blockIdx.x & 7;   // batch's 16 WGs round-robin onto one XCD
    const int w = blockIdx.x >> 3;
    const int tid = threadIdx.x;
    const int lane = tid & 63;
    const int wv = tid >> 6;
    const float* xb = xyz + (size_t)b * (K * 3);
    const int base = w * PTS;

    __shared__ unsigned long long s_wkey[T / 64];
    __shared__ float s_qx, s_qy, s_qz;

    float px[PPT], py[PPT], pz[PPT], dist[PPT];
#pragma unroll
    for (int j = 0; j < PPT; ++j) {
        int l = j * T + tid;
        int g = base + l;
        px[j] = xb[3 * g];
        py[j] = xb[3 * g + 1];
        pz[j] = xb[3 * g + 2];
        dist[j] = 1e10f;
    }
    float qx = xb[0], qy = xb[1], qz = xb[2];
    if (w == 0 && tid == 0) out[OUT_INDS + b * NPROP] = 0.0f;

    for (int t = 1; t < NPROP; ++t) {
        // ---- local distance update + per-lane argmax (bit-exact vs numpy:
        // no FMA contraction, (dx2+dy2)+dz2 order, first-max tie-break via
        // strict > over ascending l) ----
        float bestd = -1.0f;
        unsigned int bestl = 0;
#pragma unroll
        for (int j = 0; j < PPT; ++j) {
            float dx = __fsub_rn(px[j], qx);
            float dy = __fsub_rn(py[j], qy);
            float dz = __fsub_rn(pz[j], qz);
            float d = __fadd_rn(__fadd_rn(__fmul_rn(dx, dx), __fmul_rn(dy, dy)),
                                __fmul_rn(dz, dz));
            float nd = fminf(dist[j], d);
            dist[j] = nd;
            unsigned int l = (unsigned int)(j * T + tid);
            bool gt = nd > bestd;
            bestd = gt ? nd : bestd;
            bestl = gt ? l : bestl;
        }
        // ---- wave-level two-phase argmax via DPP (dist >= 0 so float order
        // == u32 bit order; phase2 max(~l) == first-max tie-break) ----
        unsigned int du = __float_as_uint(bestd);
        unsigned int m1 = wave_umax63(du);
        unsigned int maxd = (unsigned int)__builtin_amdgcn_readlane((int)m1, 63);
        unsigned int cand = (du == maxd) ? ~bestl : 0u;
        unsigned int m2 = wave_umax63(cand);

        const int par = t & 1;
        unsigned long long* mgrp = ws + (size_t)((par * BATCH + b) * M) * SLOT_STRIDE;
        unsigned long long* sgrp = mgrp + MIRROR_ULLS;
        const unsigned int tt = (unsigned int)t;

        if (lane == 63) {
            unsigned int l = ~m2;                 // wave-winner local index
            unsigned int g = (unsigned int)base + l;
            s_wkey[wv] = ((unsigned long long)maxd << 32) |
                         ((unsigned long long)((0xFFFFu - g) & 0xFFFFu) << 16) |
                         (unsigned long long)tt;
        }
        __syncthreads();   // S1

        // ---- post (wave 1, so its vmcnt traffic never stalls the polling
        // wave): key first (the detector), then safe copy, then coords ----
        if (tid == 64) {
            unsigned long long kb = s_wkey[0];
#pragma unroll
            for (int i = 1; i < T / 64; ++i) kb = (s_wkey[i] > kb) ? s_wkey[i] : kb;
            unsigned int gw = 0xFFFFu - (unsigned int)((kb >> 16) & 0xFFFFu);
            volatile unsigned long long* mme =
                (volatile unsigned long long*)(mgrp + (size_t)w * SLOT_STRIDE);
            mme[0] = kb;   // mirror key (L2 fast path)
            __hip_atomic_store(&sgrp[(size_t)w * SLOT_STRIDE], kb,
                               __ATOMIC_RELAXED, __HIP_MEMORY_SCOPE_AGENT);
            const float* cp = xb + 3 * (size_t)gw;
            float cx = cp[0], cy = cp[1], cz = cp[2];
            unsigned long long tagHi = ((unsigned long long)tt) << 32;
            mme[1] = tagHi | __float_as_uint(cz);
            mme[2] = tagHi | __float_as_uint(cx);
            mme[3] = tagHi | __float_as_uint(cy);
        }

        // ---- poll (wave 0, lanes 0..15): bounded sc0/L2 fast spin, then
        // agent-scope fallback. Every word tag-validated. ----
        if (tid < M) {
            const unsigned long long* mp = mgrp + (size_t)tid * SLOT_STRIDE;
            unsigned long long kk = 0ull;
            unsigned int zv = 0, zt = 0, xv = 0, xt = 0, yv = 0, yt = 0;
            bool have = false;
            for (int it = 0; it < FAST_ITERS && !have; ++it) {
                u32x4 a, bq;
                load_line_sc0(mp, a, bq);
                if ((a.x & 0xFFFFu) == tt) {
                    kk = ((unsigned long long)a.y << 32) | a.x;
                    zv = a.z; zt = a.w; xv = bq.x; xt = bq.y; yv = bq.z; yt = bq.w;
                    have = true;
                }
            }
            if (!have) {
                // guaranteed-progress path (r3, round-3 validated)
                unsigned long long* sp = sgrp + (size_t)tid * SLOT_STRIDE;
                unsigned long long v;
                do {
                    v = __hip_atomic_load(sp, __ATOMIC_RELAXED, __HIP_MEMORY_SCOPE_AGENT);
                } while ((unsigned short)v != (unsigned short)tt);
                kk = v;   // payload tags stay 0 -> coord fallback below
            }
            // ---- two-phase argmax over 16 keys via DPP ----
            unsigned int hi = (unsigned int)(kk >> 32);
            unsigned int lo = (unsigned int)kk;
            unsigned int p1 = row16_umax15(hi);
            unsigned int maxk = (unsigned int)__builtin_amdgcn_readlane((int)p1, 15);
            unsigned int c2 = (hi == maxk) ? lo : 0u;   // (0xFFFF-g)<<16 | t
            unsigned int p2 = row16_umax15(c2);
            unsigned int low = (unsigned int)__builtin_amdgcn_readlane((int)p2, 15);
            unsigned int g = 0xFFFFu - (low >> 16);
            int s = (int)(g >> 12);                     // winner WG/slot (PTS=4096)
            int ad = s << 2;
            // pull winner payload from the lane that polled slot s
            unsigned int wzv = (unsigned int)__builtin_amdgcn_ds_bpermute(ad, (int)zv);
            unsigned int wzt = (unsigned int)__builtin_amdgcn_ds_bpermute(ad, (int)zt);
            unsigned int wxv = (unsigned int)__builtin_amdgcn_ds_bpermute(ad, (int)xv);
            unsigned int wxt = (unsigned int)__builtin_amdgcn_ds_bpermute(ad, (int)xt);
            unsigned int wyv = (unsigned int)__builtin_amdgcn_ds_bpermute(ad, (int)yv);
            unsigned int wyt = (unsigned int)__builtin_amdgcn_ds_bpermute(ad, (int)yt);
            float wx, wy, wz;
            if (wzt == tt && wxt == tt && wyt == tt) {     // uniform branch
                wx = __uint_as_float(wxv);
                wy = __uint_as_float(wyv);
                wz = __uint_as_float(wzv);
            } else {
                // payload not yet visible: one same-address mirror re-read,
                // else coords from immutable xyz (always available, hang-free)
                u32x4 a2, b2;
                load_line_sc0(mgrp + (size_t)s * SLOT_STRIDE, a2, b2);
                if (a2.w == tt && b2.y == tt && b2.w == tt) {
                    wz = __uint_as_float(a2.z);
                    wx = __uint_as_float(b2.x);
                    wy = __uint_as_float(b2.z);
                } else {
                    const float* cp = xb + 3 * (size_t)g;
                    wx = cp[0]; wy = cp[1]; wz = cp[2];
                }
            }
            if (tid == 0) {
                s_qx = wx; s_qy = wy; s_qz = wz;
                if (w == 0) out[OUT_INDS + b * NPROP + t] = (float)g;
            }
        }
        __syncthreads();   // S2
        qx = s_qx; qy = s_qy; qz = s_qz;
    }
}

__global__ __launch_bounds__(256) void gather_kernel(const float* __restrict__ xyz,
                                                     const float* __restrict__ feat,
                                                     float* __restrict__ out) {
    int gid = blockIdx.x * 256 + threadIdx.x;   // covers B*C*N = 1,048,576
    int n = gid & (NPROP - 1);
    int b = gid >> 17;                          // C*N = 2^17
    int c = (gid >> 10) & (CFEAT - 1);
    int ind = (int)out[OUT_INDS + (b << 10) + n];   // float inds, exact < 2^24
    out[OUT_FEAT + gid] = feat[(((size_t)b * CFEAT + c) << 16) + (size_t)ind];
    if (gid < BATCH * NPROP) {
        int b2 = gid >> 10;
        int ind2 = (int)out[OUT_INDS + gid];
        const float* s = xyz + ((size_t)b2 * K + (size_t)ind2) * 3;
        float a0 = s[0], a1 = s[1], a2 = s[2];
        out[gid * 3 + 0] = a0;
        out[gid * 3 + 1] = a1;
        out[gid * 3 + 2] = a2;
    }
}

extern "C" void kernel_launch(void* const* d_in, const int* in_sizes, int n_in,
                              void* d_out, int out_size, void* d_ws, size_t ws_size,
                              hipStream_t stream) {
    const float* xyz = (const float*)d_in[0];
    const float* feat = (const float*)d_in[1];
    float* out = (float*)d_out;
    unsigned long long* ws = (unsigned long long*)d_ws;

    hipLaunchKernelGGL(fps_init, dim3(WS_ULLS / 256), dim3(256), 0, stream, ws);
    hipLaunchKernelGGL(fps_kernel, dim3(BATCH * M), dim3(T), 0, stream,
                       xyz, out, ws);
    hipLaunchKernelGGL(gather_kernel, dim3(BATCH * CFEAT * NPROP / 256), dim3(256),
                       0, stream, xyz, feat, out);
}

// Round 8
// 2021.081 us; speedup vs baseline: 2.6260x; 2.6260x over previous
//
#include <hip/hip_runtime.h>
#include <stdint.h>

#define BATCH 8
#define K 65536
#define CFEAT 128
#define NPROP 1024
#define M 16            // workgroups per batch
#define T 320           // 4 compute waves + 1 exchange wave
#define CTHREADS 256    // compute threads (waves 0-3)
#define PTS (K / M)     // 4096 points per WG
#define PPT (PTS / CTHREADS)   // 16 points per thread

// d_out layout (float32): new_xyz (B,N,3) | new_features (B,C,N) | inds (B,N) as float
#define OUT_FEAT (BATCH * NPROP * 3)                         // 24576
#define OUT_INDS (BATCH * NPROP * 3 + BATCH * CFEAT * NPROP) // 1073152

// ws layout: slot[2][BATCH][M] lines, each on its OWN 64B cacheline.
// KEY-ONLY protocol (round-3 validated, fps 1670us): word [0] =
// key { dist_u32 | (0xFFFF-g)<<16 | tag }.
// All spin-path accesses RELAXED agent-scope (acquire emits buffer_inv ->
// chip-wide L2 thrash, round-2 lesson; sc0/L2 mirroring is impossible —
// round-7 lesson: agent stores go to the coherence point and never install
// into remote L2s, so remote sc0 readers see stale lines forever).
// Exact 16-bit tag + parity double-buffer: WG w posts round t only after
// finishing its poll of round t-1, which requires every WG posted t-1,
// which requires every WG finished polling t-2 (same parity) — overwrite
// races impossible. Identical argument holds with the exchange delegated
// to wave 4 (its post of t still strictly follows its poll of t-1).
#define SLOT_STRIDE 8
#define WS_ULLS (2 * BATCH * M * SLOT_STRIDE)   // 2048 ulls = 16 KB

__global__ __launch_bounds__(256) void fps_init(unsigned long long* ws) {
    int i = blockIdx.x * 256 + threadIdx.x;
    if (i < WS_ULLS) ws[i] = 0ull;   // tag 0 never matches t in [1,1023]
}

// Wave-wide u32 max via DPP (HW-validated rounds 2-7). Max lands in lane 63.
__device__ __forceinline__ unsigned int wave_umax63(unsigned int x) {
    int v = (int)x;
    int t;
    t = __builtin_amdgcn_update_dpp(v, v, 0x111, 0xF, 0xF, false);  // row_shr:1
    v = ((unsigned)t > (unsigned)v) ? t : v;
    t = __builtin_amdgcn_update_dpp(v, v, 0x112, 0xF, 0xF, false);  // row_shr:2
    v = ((unsigned)t > (unsigned)v) ? t : v;
    t = __builtin_amdgcn_update_dpp(v, v, 0x114, 0xF, 0xF, false);  // row_shr:4
    v = ((unsigned)t > (unsigned)v) ? t : v;
    t = __builtin_amdgcn_update_dpp(v, v, 0x118, 0xF, 0xF, false);  // row_shr:8
    v = ((unsigned)t > (unsigned)v) ? t : v;
    t = __builtin_amdgcn_update_dpp(v, v, 0x142, 0xF, 0xF, false);  // row_bcast:15
    v = ((unsigned)t > (unsigned)v) ? t : v;
    t = __builtin_amdgcn_update_dpp(v, v, 0x143, 0xF, 0xF, false);  // row_bcast:31
    v = ((unsigned)t > (unsigned)v) ? t : v;
    return (unsigned int)v;
}

// 16-lane (row 0) u32 max via DPP; max of lanes 0..15 lands in lane 15.
__device__ __forceinline__ unsigned int row16_umax15(unsigned int x) {
    int v = (int)x;
    int t;
    t = __builtin_amdgcn_update_dpp(v, v, 0x111, 0xF, 0xF, false);  // row_shr:1
    v = ((unsigned)t > (unsigned)v) ? t : v;
    t = __builtin_amdgcn_update_dpp(v, v, 0x112, 0xF, 0xF, false);  // row_shr:2
    v = ((unsigned)t > (unsigned)v) ? t : v;
    t = __builtin_amdgcn_update_dpp(v, v, 0x114, 0xF, 0xF, false);  // row_shr:4
    v = ((unsigned)t > (unsigned)v) ? t : v;
    t = __builtin_amdgcn_update_dpp(v, v, 0x118, 0xF, 0xF, false);  // row_shr:8
    v = ((unsigned)t > (unsigned)v) ? t : v;
    return (unsigned int)v;
}

__global__ __launch_bounds__(T) void fps_kernel(const float* __restrict__ xyz,
                                                float* __restrict__ out,
                                                unsigned long long* __restrict__ ws) {
    const int b = blockIdx.x & 7;   // batch's 16 WGs round-robin onto one XCD
    const int w = blockIdx.x >> 3;
    const int tid = threadIdx.x;
    const int lane = tid & 63;
    const int wv = tid >> 6;        // 0..3 compute, 4 exchange
    const float* xb = xyz + (size_t)b * (K * 3);
    const int base = w * PTS;

    // Intra-WG handshake words — ALL tag-validated (low 16 bits == round t),
    // all relaxed workgroup-scope LDS atomics. Self-validating like the
    // global protocol, so no barriers and no ordering fences are needed:
    //   s_wkey[wv]: {dist | (0xFFFF-g)<<16 | tag} from each compute wave
    //   s_res:      {g<<16 | tag} published by the exchange wave
    __shared__ unsigned long long s_wkey[4];
    __shared__ unsigned int s_res;

    float px[PPT], py[PPT], pz[PPT], dist[PPT];
    if (wv < 4) {
#pragma unroll
        for (int j = 0; j < PPT; ++j) {
            int l = j * CTHREADS + tid;
            int g = base + l;
            px[j] = xb[3 * g];
            py[j] = xb[3 * g + 1];
            pz[j] = xb[3 * g + 2];
            dist[j] = 1e10f;
        }
    }
    float qx = xb[0], qy = xb[1], qz = xb[2];
    if (tid == 0) {
        s_wkey[0] = 0ull; s_wkey[1] = 0ull; s_wkey[2] = 0ull; s_wkey[3] = 0ull;
        s_res = 0u;
        if (w == 0) out[OUT_INDS + b * NPROP] = 0.0f;
    }
    __syncthreads();   // init visibility; the ONLY barrier in this kernel

    if (wv < 4) {
        // ================= compute role (waves 0-3) =================
        for (int t = 1; t < NPROP; ++t) {
            // bit-exact vs numpy: no FMA contraction, (dx2+dy2)+dz2 order,
            // first-max tie-break via strict > over ascending l
            float bestd = -1.0f;
            unsigned int bestl = 0;
#pragma unroll
            for (int j = 0; j < PPT; ++j) {
                float dx = __fsub_rn(px[j], qx);
                float dy = __fsub_rn(py[j], qy);
                float dz = __fsub_rn(pz[j], qz);
                float d = __fadd_rn(__fadd_rn(__fmul_rn(dx, dx), __fmul_rn(dy, dy)),
                                    __fmul_rn(dz, dz));
                float nd = fminf(dist[j], d);
                dist[j] = nd;
                unsigned int l = (unsigned int)(j * CTHREADS + tid);
                bool gt = nd > bestd;
                bestd = gt ? nd : bestd;
                bestl = gt ? l : bestl;
            }
            // wave-level two-phase argmax via DPP (dist >= 0 so float order
            // == u32 bit order; phase2 max(~l) == first-max tie-break)
            unsigned int du = __float_as_uint(bestd);
            unsigned int m1 = wave_umax63(du);
            unsigned int maxd = (unsigned int)__builtin_amdgcn_readlane((int)m1, 63);
            unsigned int cand = (du == maxd) ? ~bestl : 0u;
            unsigned int m2 = wave_umax63(cand);
            if (lane == 63) {
                unsigned int l = ~m2;
                unsigned int g = (unsigned int)base + l;
                unsigned long long key =
                    ((unsigned long long)maxd << 32) |
                    ((unsigned long long)((0xFFFFu - g) & 0xFFFFu) << 16) |
                    (unsigned long long)(unsigned int)t;
                __hip_atomic_store(&s_wkey[wv], key, __ATOMIC_RELAXED,
                                   __HIP_MEMORY_SCOPE_WORKGROUP);
            }
            // wait for the exchange wave's verdict (tag-validated LDS spin,
            // ~60cy sampling — no barrier park/wake, no waitcnt drain)
            unsigned int r;
            do {
                r = __hip_atomic_load(&s_res, __ATOMIC_RELAXED,
                                      __HIP_MEMORY_SCOPE_WORKGROUP);
            } while ((r & 0xFFFFu) != (unsigned int)t);
            unsigned int g = r >> 16;
            qx = xb[3 * g];
            qy = xb[3 * g + 1];
            qz = xb[3 * g + 2];
        }
    } else {
        // ================= exchange role (wave 4) =================
        for (int t = 1; t < NPROP; ++t) {
            const int par = t & 1;
            unsigned long long* sgrp =
                ws + (size_t)((par * BATCH + b) * M) * SLOT_STRIDE;
            const unsigned int tt = (unsigned int)t;
            if (lane < M) {
                // lane i watches local key (i&3); exits when tag==t.
                // Keys are write-once per round, so matched-stays-matched.
                unsigned long long kk;
                do {
                    kk = __hip_atomic_load(&s_wkey[lane & 3], __ATOMIC_RELAXED,
                                           __HIP_MEMORY_SCOPE_WORKGROUP);
                } while ((kk & 0xFFFFu) != (unsigned long long)tt);
                unsigned int hi = (unsigned int)(kk >> 32);
                unsigned int lo = (unsigned int)kk;
                // two-phase max over the 4 keys (each replicated 4x in lanes)
                unsigned int p1 = row16_umax15(hi);
                unsigned int mh = (unsigned int)__builtin_amdgcn_readlane((int)p1, 15);
                unsigned int c2 = (hi == mh) ? lo : 0u;
                unsigned int p2 = row16_umax15(c2);
                unsigned int ml = (unsigned int)__builtin_amdgcn_readlane((int)p2, 15);
                if (lane == 0) {
                    unsigned long long kb = ((unsigned long long)mh << 32) |
                                            (unsigned long long)ml;
                    __hip_atomic_store(&sgrp[(size_t)w * SLOT_STRIDE], kb,
                                       __ATOMIC_RELAXED, __HIP_MEMORY_SCOPE_AGENT);
                }
                // global exchange: dependent spin, own-slot bypass
                unsigned int khi, klo;
                if (lane == w) {
                    khi = mh; klo = ml;
                } else {
                    unsigned long long* sp = sgrp + (size_t)lane * SLOT_STRIDE;
                    unsigned long long v;
                    do {
                        v = __hip_atomic_load(sp, __ATOMIC_RELAXED,
                                              __HIP_MEMORY_SCOPE_AGENT);
                    } while ((unsigned short)v != (unsigned short)tt);
                    khi = (unsigned int)(v >> 32);
                    klo = (unsigned int)v;
                }
                // two-phase argmax over the 16 WG keys
                unsigned int q1 = row16_umax15(khi);
                unsigned int qh = (unsigned int)__builtin_amdgcn_readlane((int)q1, 15);
                unsigned int d2 = (khi == qh) ? klo : 0u;   // (0xFFFF-g)<<16 | t
                unsigned int q2 = row16_umax15(d2);
                unsigned int ql = (unsigned int)__builtin_amdgcn_readlane((int)q2, 15);
                unsigned int g = 0xFFFFu - (ql >> 16);
                if (lane == 0) {
                    __hip_atomic_store(&s_res, (g << 16) | tt, __ATOMIC_RELAXED,
                                       __HIP_MEMORY_SCOPE_WORKGROUP);
                    if (w == 0) out[OUT_INDS + b * NPROP + t] = (float)g;
                }
            }
        }
    }
}

__global__ __launch_bounds__(256) void gather_kernel(const float* __restrict__ xyz,
                                                     const float* __restrict__ feat,
                                                     float* __restrict__ out) {
    int gid = blockIdx.x * 256 + threadIdx.x;   // covers B*C*N = 1,048,576
    int n = gid & (NPROP - 1);
    int b = gid >> 17;                          // C*N = 2^17
    int c = (gid >> 10) & (CFEAT - 1);
    int ind = (int)out[OUT_INDS + (b << 10) + n];   // float inds, exact < 2^24
    out[OUT_FEAT + gid] = feat[(((size_t)b * CFEAT + c) << 16) + (size_t)ind];
    if (gid < BATCH * NPROP) {
        int b2 = gid >> 10;
        int ind2 = (int)out[OUT_INDS + gid];
        const float* s = xyz + ((size_t)b2 * K + (size_t)ind2) * 3;
        float a0 = s[0], a1 = s[1], a2 = s[2];
        out[gid * 3 + 0] = a0;
        out[gid * 3 + 1] = a1;
        out[gid * 3 + 2] = a2;
    }
}

extern "C" void kernel_launch(void* const* d_in, const int* in_sizes, int n_in,
                              void* d_out, int out_size, void* d_ws, size_t ws_size,
                              hipStream_t stream) {
    const float* xyz = (const float*)d_in[0];
    const float* feat = (const float*)d_in[1];
    float* out = (float*)d_out;
    unsigned long long* ws = (unsigned long long*)d_ws;

    hipLaunchKernelGGL(fps_init, dim3(WS_ULLS / 256), dim3(256), 0, stream, ws);
    hipLaunchKernelGGL(fps_kernel, dim3(BATCH * M), dim3(T), 0, stream,
                       xyz, out, ws);
    hipLaunchKernelGGL(gather_kernel, dim3(BATCH * CFEAT * NPROP / 256), dim3(256),
                       0, stream, xyz, feat, out);
}

// Round 10
// 1734.578 us; speedup vs baseline: 3.0598x; 1.1652x over previous
//
#include <hip/hip_runtime.h>
#include <stdint.h>

#define BATCH 8
#define K 65536
#define CFEAT 128
#define NPROP 1024
#define M 16            // workgroups per batch
#define T 320           // 4 compute waves + 1 exchange wave
#define CTHREADS 256    // compute threads (waves 0-3)
#define PTS (K / M)     // 4096 points per WG
#define PPT (PTS / CTHREADS)   // 16 points per thread
#define NSLOT 64        // one global slot per COMPUTE WAVE per batch

// d_out layout (float32): new_xyz (B,N,3) | new_features (B,C,N) | inds (B,N) as float
#define OUT_FEAT (BATCH * NPROP * 3)                         // 24576
#define OUT_INDS (BATCH * NPROP * 3 + BATCH * CFEAT * NPROP) // 1073152

// ws layout: slot[2][BATCH][NSLOT] lines, each on its OWN 64B cacheline.
// KEY-ONLY protocol (round-3 validated): key { dist_u32 | (0xFFFF-g)<<16 | tag }.
// NEW vs r3/r8: each compute WAVE posts directly to its own slot (no intra-WG
// collect on the post path — the system-wide critical path is gated by the
// slowest poster, so the LDS handoff + cross-wave scan is deleted from it).
// The per-WG exchange wave polls all 64 slots (one per lane), gated on local
// compute completion + ~384cy sleep so it samples ~1-2x per round (r3 FETCH
// showed detection needs <1 sample once arrivals are aligned; ungated
// polling would 4x the coherence traffic for nothing).
// All spin-path accesses RELAXED agent-scope (acquire emits buffer_inv ->
// chip-wide L2 thrash, r2 lesson; sc0/L2 mirroring impossible — r7 lesson:
// agent stores install at the coherence point only, remote L2s stay stale).
// Exact 16-bit tag + parity double-buffer: a wave posts round t+1 only after
// its WG consumed s_res(t), which required ALL 64 posts of t visible, which
// required every WG consumed t-1 (same parity as t+1) — overwrite races
// impossible. Stale same-parity reads show tag t-2 and are rejected.
#define SLOT_STRIDE 8
#define WS_ULLS (2 * BATCH * NSLOT * SLOT_STRIDE)   // 8192 ulls = 64 KB

__global__ __launch_bounds__(256) void fps_init(unsigned long long* ws) {
    int i = blockIdx.x * 256 + threadIdx.x;
    if (i < WS_ULLS) ws[i] = 0ull;   // tag 0 never matches t in [1,1023]
}

// Wave-wide u32 max via DPP (HW-validated rounds 2-8). Max lands in lane 63.
__device__ __forceinline__ unsigned int wave_umax63(unsigned int x) {
    int v = (int)x;
    int t;
    t = __builtin_amdgcn_update_dpp(v, v, 0x111, 0xF, 0xF, false);  // row_shr:1
    v = ((unsigned)t > (unsigned)v) ? t : v;
    t = __builtin_amdgcn_update_dpp(v, v, 0x112, 0xF, 0xF, false);  // row_shr:2
    v = ((unsigned)t > (unsigned)v) ? t : v;
    t = __builtin_amdgcn_update_dpp(v, v, 0x114, 0xF, 0xF, false);  // row_shr:4
    v = ((unsigned)t > (unsigned)v) ? t : v;
    t = __builtin_amdgcn_update_dpp(v, v, 0x118, 0xF, 0xF, false);  // row_shr:8
    v = ((unsigned)t > (unsigned)v) ? t : v;
    t = __builtin_amdgcn_update_dpp(v, v, 0x142, 0xF, 0xF, false);  // row_bcast:15
    v = ((unsigned)t > (unsigned)v) ? t : v;
    t = __builtin_amdgcn_update_dpp(v, v, 0x143, 0xF, 0xF, false);  // row_bcast:31
    v = ((unsigned)t > (unsigned)v) ? t : v;
    return (unsigned int)v;
}

__global__ __launch_bounds__(T) void fps_kernel(const float* __restrict__ xyz,
                                                float* __restrict__ out,
                                                unsigned long long* __restrict__ ws) {
    const int b = blockIdx.x & 7;   // batch's 16 WGs round-robin onto one XCD
    const int w = blockIdx.x >> 3;
    const int tid = threadIdx.x;
    const int lane = tid & 63;
    const int wv = tid >> 6;        // 0..3 compute, 4 exchange
    const float* xb = xyz + (size_t)b * (K * 3);
    const int base = w * PTS;

    // Intra-WG handshake, all tag-validated relaxed LDS (r8-validated):
    //   s_wkey[wv]: local copy of each compute wave's key (poll-start gate)
    //   s_res:      {g<<16 | tag} published by the exchange wave
    __shared__ unsigned long long s_wkey[4];
    __shared__ unsigned int s_res;

    if (tid == 0) {
        s_wkey[0] = 0ull; s_wkey[1] = 0ull; s_wkey[2] = 0ull; s_wkey[3] = 0ull;
        s_res = 0u;
        if (w == 0) out[OUT_INDS + b * NPROP] = 0.0f;
    }
    __syncthreads();   // init visibility; the ONLY barrier in this kernel

    if (wv < 4) {
        // ================= compute role (waves 0-3) =================
        float px[PPT], py[PPT], pz[PPT], dist[PPT];
#pragma unroll
        for (int j = 0; j < PPT; ++j) {
            int l = j * CTHREADS + tid;
            int g = base + l;
            px[j] = xb[3 * g];
            py[j] = xb[3 * g + 1];
            pz[j] = xb[3 * g + 2];
            dist[j] = 1e10f;
        }
        float qx = xb[0], qy = xb[1], qz = xb[2];

        for (int t = 1; t < NPROP; ++t) {
            // bit-exact vs numpy: no FMA contraction, (dx2+dy2)+dz2 order,
            // first-max tie-break via strict > over ascending l
            float bestd = -1.0f;
            unsigned int bestl = 0;
#pragma unroll
            for (int j = 0; j < PPT; ++j) {
                float dx = __fsub_rn(px[j], qx);
                float dy = __fsub_rn(py[j], qy);
                float dz = __fsub_rn(pz[j], qz);
                float d = __fadd_rn(__fadd_rn(__fmul_rn(dx, dx), __fmul_rn(dy, dy)),
                                    __fmul_rn(dz, dz));
                float nd = fminf(dist[j], d);
                dist[j] = nd;
                unsigned int l = (unsigned int)(j * CTHREADS + tid);
                bool gt = nd > bestd;
                bestd = gt ? nd : bestd;
                bestl = gt ? l : bestl;
            }
            // wave-level two-phase argmax via DPP (dist >= 0 so float order
            // == u32 bit order; phase2 max(~l) == first-max tie-break)
            unsigned int du = __float_as_uint(bestd);
            unsigned int m1 = wave_umax63(du);
            unsigned int maxd = (unsigned int)__builtin_amdgcn_readlane((int)m1, 63);
            unsigned int cand = (du == maxd) ? ~bestl : 0u;
            unsigned int m2 = wave_umax63(cand);
            if (lane == 63) {
                unsigned int l = ~m2;
                unsigned int g = (unsigned int)base + l;
                unsigned long long key =
                    ((unsigned long long)maxd << 32) |
                    ((unsigned long long)((0xFFFFu - g) & 0xFFFFu) << 16) |
                    (unsigned long long)(unsigned int)t;
                // direct per-wave global post — the intra-WG collect is OFF
                // the system critical path entirely
                __hip_atomic_store(
                    &ws[((size_t)(((t & 1) * BATCH + b) * NSLOT) +
                         (size_t)(w * 4 + wv)) * SLOT_STRIDE],
                    key, __ATOMIC_RELAXED, __HIP_MEMORY_SCOPE_AGENT);
                // LDS copy = exchange wave's poll-start gate
                __hip_atomic_store(&s_wkey[wv], key, __ATOMIC_RELAXED,
                                   __HIP_MEMORY_SCOPE_WORKGROUP);
            }
            // wait for the verdict (tag-validated LDS spin)
            unsigned int r;
            do {
                r = __hip_atomic_load(&s_res, __ATOMIC_RELAXED,
                                      __HIP_MEMORY_SCOPE_WORKGROUP);
            } while ((r & 0xFFFFu) != (unsigned int)t);
            unsigned int g = r >> 16;
            qx = xb[3 * g];
            qy = xb[3 * g + 1];
            qz = xb[3 * g + 2];
        }
    } else {
        // ================= exchange role (wave 4) =================
        for (int t = 1; t < NPROP; ++t) {
            const unsigned int tt = (unsigned int)t;
            unsigned long long* sgrp =
                ws + (size_t)(((t & 1) * BATCH + b) * NSLOT) * SLOT_STRIDE;
            // poll-start gate: local compute done (matched-stays-matched);
            // wave-level exec => ALL 64 lanes held here until lanes 0-3 exit
            if (lane < 4) {
                unsigned long long kk;
                do {
                    kk = __hip_atomic_load(&s_wkey[lane], __ATOMIC_RELAXED,
                                           __HIP_MEMORY_SCOPE_WORKGROUP);
                } while ((kk & 0xFFFFu) != (unsigned long long)tt);
            }
            __builtin_amdgcn_s_sleep(6);   // ~384cy: skip the store-flight window
            // all 64 lanes poll one slot each (8B dependent spin, exact tag)
            unsigned long long* sp = sgrp + (size_t)lane * SLOT_STRIDE;
            unsigned long long v;
            do {
                v = __hip_atomic_load(sp, __ATOMIC_RELAXED,
                                      __HIP_MEMORY_SCOPE_AGENT);
            } while ((unsigned short)v != (unsigned short)tt);
            // two-phase argmax over all 64 wave keys
            unsigned int hi = (unsigned int)(v >> 32);
            unsigned int lo = (unsigned int)v;
            unsigned int p1 = wave_umax63(hi);
            unsigned int mh = (unsigned int)__builtin_amdgcn_readlane((int)p1, 63);
            unsigned int c2 = (hi == mh) ? lo : 0u;   // (0xFFFF-g)<<16 | t
            unsigned int p2 = wave_umax63(c2);
            unsigned int ml = (unsigned int)__builtin_amdgcn_readlane((int)p2, 63);
            unsigned int g = 0xFFFFu - (ml >> 16);
            if (lane == 0) {
                __hip_atomic_store(&s_res, (g << 16) | tt, __ATOMIC_RELAXED,
                                   __HIP_MEMORY_SCOPE_WORKGROUP);
                if (w == 0) out[OUT_INDS + b * NPROP + t] = (float)g;
            }
        }
    }
}

__global__ __launch_bounds__(256) void gather_kernel(const float* __restrict__ xyz,
                                                     const float* __restrict__ feat,
                                                     float* __restrict__ out) {
    int gid = blockIdx.x * 256 + threadIdx.x;   // covers B*C*N = 1,048,576
    int n = gid & (NPROP - 1);
    int b = gid >> 17;                          // C*N = 2^17
    int c = (gid >> 10) & (CFEAT - 1);
    int ind = (int)out[OUT_INDS + (b << 10) + n];   // float inds, exact < 2^24
    out[OUT_FEAT + gid] = feat[(((size_t)b * CFEAT + c) << 16) + (size_t)ind];
    if (gid < BATCH * NPROP) {
        int b2 = gid >> 10;
        int ind2 = (int)out[OUT_INDS + gid];
        const float* s = xyz + ((size_t)b2 * K + (size_t)ind2) * 3;
        float a0 = s[0], a1 = s[1], a2 = s[2];
        out[gid * 3 + 0] = a0;
        out[gid * 3 + 1] = a1;
        out[gid * 3 + 2] = a2;
    }
}

extern "C" void kernel_launch(void* const* d_in, const int* in_sizes, int n_in,
                              void* d_out, int out_size, void* d_ws, size_t ws_size,
                              hipStream_t stream) {
    const float* xyz = (const float*)d_in[0];
    const float* feat = (const float*)d_in[1];
    float* out = (float*)d_out;
    unsigned long long* ws = (unsigned long long*)d_ws;

    hipLaunchKernelGGL(fps_init, dim3(WS_ULLS / 256), dim3(256), 0, stream, ws);
    hipLaunchKernelGGL(fps_kernel, dim3(BATCH * M), dim3(T), 0, stream,
                       xyz, out, ws);
    hipLaunchKernelGGL(gather_kernel, dim3(BATCH * CFEAT * NPROP / 256), dim3(256),
                       0, stream, xyz, feat, out);
}